// Round 1
// baseline (652.265 us; speedup 1.0000x reference)
//
#include <hip/hip_runtime.h>
#include <hip/hip_bf16.h>

// Problem constants
#define B_    1024
#define DIMC  64      // DIM
#define T_    255     // S-1 sequence steps
#define H_    128
#define CS_   500
#define S_    256

#define MROWS 16      // batch rows per block
#define NBLK  (B_ / MROWS)   // 64 blocks
#define NTHR  512            // 8 waves
#define XSTR  136            // padded LDS row stride (bf16 elems): +8 pad -> 2-way max bank alias

typedef __attribute__((ext_vector_type(8))) short bf16x8;
typedef __attribute__((ext_vector_type(4))) float f32x4;

__device__ __forceinline__ unsigned short f2bf(float f) {
    unsigned int u = __builtin_bit_cast(unsigned int, f);
    unsigned int r = (u + 0x7FFFu + ((u >> 16) & 1u)) >> 16;
    return (unsigned short)r;
}

__device__ __forceinline__ float fast_rcp(float x) { return __builtin_amdgcn_rcpf(x); }
__device__ __forceinline__ float sigm(float x)   { float e = __expf(-x); return fast_rcp(1.0f + e); }
__device__ __forceinline__ float tanh_f(float x) { float e = __expf(2.0f * x); return 1.0f - 2.0f * fast_rcp(1.0f + e); }
__device__ __forceinline__ float leaky(float x)  { return x > 0.0f ? x : 0.01f * x; }

__global__ __launch_bounds__(NTHR, 2)
void gru_fused(const float* __restrict__ x, const int* __restrict__ snippet,
               const float* __restrict__ slist,
               const float* __restrict__ W_ih, const float* __restrict__ W_hh,
               const float* __restrict__ b_ih, const float* __restrict__ b_hh,
               const float* __restrict__ W1, const float* __restrict__ b1,
               const float* __restrict__ W2, const float* __restrict__ b2,
               const float* __restrict__ W3, const float* __restrict__ b3,
               const float* __restrict__ Wl, const float* __restrict__ bl,
               float* __restrict__ out)
{
    __shared__ __attribute__((aligned(16))) unsigned short sh_x[MROWS * XSTR]; // input tile bf16
    __shared__ __attribute__((aligned(16))) unsigned short sh_h[MROWS * XSTR]; // h bf16
    __shared__ __attribute__((aligned(16))) float sh_hf[MROWS * H_];           // h fp32 state
    __shared__ int   sh_idx[MROWS * DIMC];
    __shared__ float sh_s1[8][64];
    __shared__ float sh_s2[8][32];
    __shared__ float sh_s3[8][16];
    __shared__ float sh_sl[8][64];

    const int tid   = threadIdx.x;
    const int bbase = blockIdx.x * MROWS;

    // ---- load snippet indices (int32 per harness convention), zero h ----
    for (int i = tid; i < MROWS * DIMC; i += NTHR) {
        int r = i >> 6, d = i & 63;
        sh_idx[i] = snippet[(bbase + r) * DIMC + d];
    }
    for (int i = tid; i < MROWS * H_; i += NTHR) sh_hf[i] = 0.0f;
    for (int i = tid; i < MROWS * XSTR; i += NTHR) sh_h[i] = 0;

    const int lane = tid & 63;
    const int wv   = tid >> 6;          // wave 0..7
    const int l15  = lane & 15;
    const int l4   = lane >> 4;

    // ---- load weight B-fragments into registers (held whole kernel) ----
    // B-frag for tile (gate gt, k-block kb): lane holds W[g][k], g = gt*128 + wv*16 + l15,
    // k = kb*32 + l4*8 + e  (e = 0..7)
    bf16x8 wih[3][4], whh[3][4];
    {
        const int g = (wv << 4) + l15;
#pragma unroll
        for (int gt = 0; gt < 3; ++gt) {
#pragma unroll
            for (int kb = 0; kb < 4; ++kb) {
                const float* p1 = W_ih + (size_t)(gt * 128 + g) * 128 + kb * 32 + (l4 << 3);
                const float* p2 = W_hh + (size_t)(gt * 128 + g) * 128 + kb * 32 + (l4 << 3);
                bf16x8 a, b;
#pragma unroll
                for (int e = 0; e < 8; ++e) { a[e] = (short)f2bf(p1[e]); b[e] = (short)f2bf(p2[e]); }
                wih[gt][kb] = a; whh[gt][kb] = b;
            }
        }
    }

    // per-lane gate biases (column jj of hidden dim)
    const int jj = (wv << 4) + l15;
    const float bias_r = b_ih[jj]       + b_hh[jj];
    const float bias_z = b_ih[128 + jj] + b_hh[128 + jj];
    const float bxn    = b_ih[256 + jj];
    const float bhn    = b_hh[256 + jj];

    __syncthreads();   // sh_idx ready, h zeroed

    // ---- staging source pointers: thread stages 4 elems (row, kq..kq+3), advances 1 elem/step
    const int srow = tid >> 5;            // 0..15
    const int kq   = (tid & 31) << 2;     // 0..124
    const float* src0; const float* src1; const float* src2; const float* src3;
    if (kq < DIMC) {
        const float* p = x + ((size_t)(bbase + srow) * DIMC + kq) * T_;
        src0 = p; src1 = p + T_; src2 = p + 2 * T_; src3 = p + 3 * T_;
    } else {
        const int d = kq - DIMC;
        src0 = slist + ((size_t)(d + 0) * CS_ + sh_idx[(srow << 6) + d + 0]) * S_;
        src1 = slist + ((size_t)(d + 1) * CS_ + sh_idx[(srow << 6) + d + 1]) * S_;
        src2 = slist + ((size_t)(d + 2) * CS_ + sh_idx[(srow << 6) + d + 2]) * S_;
        src3 = slist + ((size_t)(d + 3) * CS_ + sh_idx[(srow << 6) + d + 3]) * S_;
    }

    // ---- main recurrence ----
    for (int t = 0; t < T_; ++t) {
        // (a) stage xc_t tile (16 x 128) as bf16 into LDS
        {
            float v0 = src0[t], v1 = src1[t], v2 = src2[t], v3 = src3[t];
            unsigned long long pk =
                (unsigned long long)(f2bf(v0) | ((unsigned)f2bf(v1) << 16)) |
                ((unsigned long long)(f2bf(v2) | ((unsigned)f2bf(v3) << 16)) << 32);
            *(unsigned long long*)&sh_x[srow * XSTR + kq] = pk;
        }
        __syncthreads();   // (b)

        // (c) read A-fragments, MFMA, gates
        bf16x8 ax[4], ah[4];
#pragma unroll
        for (int kb = 0; kb < 4; ++kb) {
            ax[kb] = *(const bf16x8*)&sh_x[l15 * XSTR + kb * 32 + (l4 << 3)];
            ah[kb] = *(const bf16x8*)&sh_h[l15 * XSTR + kb * 32 + (l4 << 3)];
        }
        f32x4 ar = {0.f, 0.f, 0.f, 0.f}, az = ar, axn = ar, ahn = ar;
#pragma unroll
        for (int kb = 0; kb < 4; ++kb) {
            ar  = __builtin_amdgcn_mfma_f32_16x16x32_bf16(ax[kb], wih[0][kb], ar,  0, 0, 0);
            az  = __builtin_amdgcn_mfma_f32_16x16x32_bf16(ax[kb], wih[1][kb], az,  0, 0, 0);
            axn = __builtin_amdgcn_mfma_f32_16x16x32_bf16(ax[kb], wih[2][kb], axn, 0, 0, 0);
            ar  = __builtin_amdgcn_mfma_f32_16x16x32_bf16(ah[kb], whh[0][kb], ar,  0, 0, 0);
            az  = __builtin_amdgcn_mfma_f32_16x16x32_bf16(ah[kb], whh[1][kb], az,  0, 0, 0);
            ahn = __builtin_amdgcn_mfma_f32_16x16x32_bf16(ah[kb], whh[2][kb], ahn, 0, 0, 0);
        }
        // gates: D layout col = l15 (-> jj), row = l4*4 + q
        float hnew[4];
#pragma unroll
        for (int q = 0; q < 4; ++q) {
            int m = (l4 << 2) + q;
            float r = sigm(ar[q] + bias_r);
            float z = sigm(az[q] + bias_z);
            float n = tanh_f(axn[q] + bxn + r * (ahn[q] + bhn));
            float ho = sh_hf[m * H_ + jj];
            hnew[q] = (1.0f - z) * n + z * ho;
        }
        __syncthreads();   // (d) all reads of sh_h/sh_hf/sh_x done
        // (e) write new h
#pragma unroll
        for (int q = 0; q < 4; ++q) {
            int m = (l4 << 2) + q;
            sh_hf[m * H_ + jj]  = hnew[q];
            sh_h[m * XSTR + jj] = (unsigned short)f2bf(hnew[q]);
        }
    }
    __syncthreads();

    // ---- fused MLP head: wave wv handles rows 2*wv, 2*wv+1 ----
    for (int mloc = 0; mloc < 2; ++mloc) {
        const int m = (wv << 1) + mloc;
        // stage 1: h1[64] = leaky(h @ W1^T + b1)
        {
            float s = b1[lane];
            const float* w = W1 + (size_t)lane * 128;
            for (int k = 0; k < 128; ++k) s += sh_hf[m * H_ + k] * w[k];
            sh_s1[wv][lane] = leaky(s);
        }
        __syncthreads();
        // stage 2: h2[32]; lanes 32..63 gather 'last' (t=255) values
        if (lane < 32) {
            float s = b2[lane];
            const float* w = W2 + (size_t)lane * 64;
            for (int k = 0; k < 64; ++k) s += sh_s1[wv][k] * w[k];
            sh_s2[wv][lane] = leaky(s);
        } else {
            int d = lane - 32;
            sh_sl[wv][d]    = slist[((size_t)d * CS_    + sh_idx[(m << 6) + d])    * S_ + (S_ - 1)];
            sh_sl[wv][lane] = slist[((size_t)lane * CS_ + sh_idx[(m << 6) + lane]) * S_ + (S_ - 1)];
        }
        __syncthreads();
        // stage 3: h3[16]
        if (lane < 16) {
            float s = b3[lane];
            const float* w = W3 + (size_t)lane * 32;
            for (int k = 0; k < 32; ++k) s += sh_s2[wv][k] * w[k];
            sh_s3[wv][lane] = leaky(s);
        }
        __syncthreads();
        // out: concat(h3[16], last[64]) @ W_last^T + b_last
        {
            float s = bl[lane];
            const float* w = Wl + (size_t)lane * 80;
#pragma unroll
            for (int i = 0; i < 16; ++i) s += sh_s3[wv][i] * w[i];
            for (int d = 0; d < 64; ++d) s += sh_sl[wv][d] * w[16 + d];
            out[(size_t)(bbase + m) * DIMC + lane] = leaky(s);
        }
        __syncthreads();
    }
}

extern "C" void kernel_launch(void* const* d_in, const int* in_sizes, int n_in,
                              void* d_out, int out_size, void* d_ws, size_t ws_size,
                              hipStream_t stream) {
    (void)in_sizes; (void)n_in; (void)out_size; (void)d_ws; (void)ws_size;
    const float* x       = (const float*)d_in[0];
    const int*   snippet = (const int*)  d_in[1];
    const float* slist   = (const float*)d_in[2];
    const float* W_ih    = (const float*)d_in[3];
    const float* W_hh    = (const float*)d_in[4];
    const float* b_ih    = (const float*)d_in[5];
    const float* b_hh    = (const float*)d_in[6];
    const float* W1      = (const float*)d_in[7];
    const float* b1      = (const float*)d_in[8];
    const float* W2      = (const float*)d_in[9];
    const float* b2      = (const float*)d_in[10];
    const float* W3      = (const float*)d_in[11];
    const float* b3      = (const float*)d_in[12];
    const float* Wl      = (const float*)d_in[13];
    const float* bl      = (const float*)d_in[14];
    float* out = (float*)d_out;

    hipLaunchKernelGGL(gru_fused, dim3(NBLK), dim3(NTHR), 0, stream,
                       x, snippet, slist, W_ih, W_hh, b_ih, b_hh,
                       W1, b1, W2, b2, W3, b3, Wl, bl, out);
}

// Round 2
// 308.503 us; speedup vs baseline: 2.1143x; 2.1143x over previous
//
#include <hip/hip_runtime.h>
#include <hip/hip_bf16.h>

// Problem constants
#define B_    1024
#define DIMC  64      // DIM
#define T_    255     // S-1 sequence steps
#define H_    128
#define CS_   500
#define S_    256

#define MROWS 16             // batch rows per block
#define NBLK  (B_ / MROWS)   // 64 blocks
#define NTHR  512            // 8 waves
#define TCH   16             // timesteps staged per chunk
#define XSTR  136            // padded LDS row stride (bf16 elems)

typedef __attribute__((ext_vector_type(8))) short bf16x8;
typedef __attribute__((ext_vector_type(4))) float f32x4;
typedef __attribute__((ext_vector_type(4))) float fv4;

__device__ __forceinline__ unsigned short f2bf(float f) {
    unsigned int u = __builtin_bit_cast(unsigned int, f);
    return (unsigned short)((u + 0x7FFFu + ((u >> 16) & 1u)) >> 16);
}
__device__ __forceinline__ float fast_rcp(float x) { return __builtin_amdgcn_rcpf(x); }
__device__ __forceinline__ float sigm(float x)   { float e = __expf(-x); return fast_rcp(1.0f + e); }
__device__ __forceinline__ float tanh_f(float x) { float e = __expf(2.0f * x); return 1.0f - 2.0f * fast_rcp(1.0f + e); }
__device__ __forceinline__ float leaky(float x)  { return x > 0.0f ? x : 0.01f * x; }
__device__ __forceinline__ int   imin(int a, int b) { return a < b ? a : b; }

// Epilogue LDS layout (dword offsets into reused sh_x area)
#define OW1 0        // W1 padded 64 x 129
#define OW2 8256     // W2 padded 32 x 65
#define OW3 10336    // W3 padded 16 x 33
#define OWL 10864    // W_last padded 64 x 81
#define OHF 16048    // h fp32, 16 x 128
#define OS1 18096    // s1 per wave 8 x 64
#define OS2 18608    // s2 per wave 8 x 32
#define OS3 18864    // s3 per wave 8 x 16
#define OSL 18992    // last per wave 8 x 64

__global__ __launch_bounds__(NTHR, 2)
void gru_fused(const float* __restrict__ x, const int* __restrict__ snippet,
               const float* __restrict__ slist,
               const float* __restrict__ W_ih, const float* __restrict__ W_hh,
               const float* __restrict__ b_ih, const float* __restrict__ b_hh,
               const float* __restrict__ W1, const float* __restrict__ b1,
               const float* __restrict__ W2, const float* __restrict__ b2,
               const float* __restrict__ W3, const float* __restrict__ b3,
               const float* __restrict__ Wl, const float* __restrict__ bl,
               float* __restrict__ out)
{
    __shared__ __attribute__((aligned(16))) unsigned short sh_x[2][TCH * MROWS * XSTR]; // 139264 B
    __shared__ __attribute__((aligned(16))) unsigned short sh_h[2][MROWS * XSTR];       // 8704 B
    __shared__ int sh_idx[MROWS * DIMC];                                                // 4096 B

    const int tid   = threadIdx.x;
    const int bbase = blockIdx.x * MROWS;
    const int lane  = tid & 63;
    const int wv    = tid >> 6;
    const int l15   = lane & 15;
    const int l4    = lane >> 4;

    // ---- snippet indices, zero h buffer 0 ----
    for (int i = tid; i < MROWS * DIMC; i += NTHR) {
        int r = i >> 6, d = i & 63;
        sh_idx[i] = snippet[(bbase + r) * DIMC + d];
    }
    for (int i = tid; i < MROWS * XSTR; i += NTHR) sh_h[0][i] = 0;

    // ---- weight B-fragments in registers (whole kernel) ----
    bf16x8 wih[3][4], whh[3][4];
    {
        const int g = (wv << 4) + l15;
#pragma unroll
        for (int gt = 0; gt < 3; ++gt) {
#pragma unroll
            for (int kb = 0; kb < 4; ++kb) {
                const float* p1 = W_ih + (size_t)(gt * 128 + g) * 128 + kb * 32 + (l4 << 3);
                const float* p2 = W_hh + (size_t)(gt * 128 + g) * 128 + kb * 32 + (l4 << 3);
                bf16x8 a, b;
#pragma unroll
                for (int e = 0; e < 8; ++e) { a[e] = (short)f2bf(p1[e]); b[e] = (short)f2bf(p2[e]); }
                wih[gt][kb] = a; whh[gt][kb] = b;
            }
        }
    }
    const int jj = (wv << 4) + l15;
    const float bias_r = b_ih[jj]       + b_hh[jj];
    const float bias_z = b_ih[128 + jj] + b_hh[128 + jj];
    const float bxn    = b_ih[256 + jj];
    const float bhn    = b_hh[256 + jj];

    __syncthreads();   // sh_idx ready, h0 zeroed

    // ---- staging unit setup: 2 units/thread, unit = (row, even k0) covering k0,k0+1 ----
    int rowu[2], k0u[2], isx[2];
    const float* pa[2]; const float* pb[2];
#pragma unroll
    for (int un = 0; un < 2; ++un) {
        int u  = tid + un * NTHR;
        int r  = u >> 6;
        int k0 = (u & 63) << 1;
        rowu[un] = r; k0u[un] = k0;
        if (k0 < DIMC) {
            isx[un] = 1;
            pa[un] = x + ((size_t)(bbase + r) * DIMC + k0) * T_;
            pb[un] = pa[un] + T_;
        } else {
            isx[un] = 0;
            int d = k0 - DIMC;
            pa[un] = slist + ((size_t)d       * CS_ + sh_idx[(r << 6) + d])     * S_;
            pb[un] = slist + ((size_t)(d + 1) * CS_ + sh_idx[(r << 6) + d + 1]) * S_;
        }
    }

    fv4 sa[2][4], sb[2][4];   // staged 16 timesteps x 2 k each, fp32

    auto issue = [&](int t0) {
#pragma unroll
        for (int un = 0; un < 2; ++un) {
#pragma unroll
            for (int g = 0; g < 4; ++g) {
                int off = t0 + g * 4;
                if (isx[un] && off + 3 > T_ - 1) {    // x rows have only 255 elems; clamp tail
                    fv4 va, vb;
#pragma unroll
                    for (int e = 0; e < 4; ++e) {
                        int tt = imin(off + e, T_ - 1);
                        va[e] = pa[un][tt]; vb[e] = pb[un][tt];
                    }
                    sa[un][g] = va; sb[un][g] = vb;
                } else {
                    fv4 va, vb;
                    __builtin_memcpy(&va, pa[un] + off, 16);
                    __builtin_memcpy(&vb, pb[un] + off, 16);
                    sa[un][g] = va; sb[un][g] = vb;
                }
            }
        }
    };

    auto commit = [&](int buf) {
#pragma unroll
        for (int un = 0; un < 2; ++un) {
#pragma unroll
            for (int g = 0; g < 4; ++g) {
#pragma unroll
                for (int e = 0; e < 4; ++e) {
                    int t = g * 4 + e;
                    unsigned pk = (unsigned)f2bf(sa[un][g][e]) | ((unsigned)f2bf(sb[un][g][e]) << 16);
                    *(unsigned*)&sh_x[buf][(t * MROWS + rowu[un]) * XSTR + k0u[un]] = pk;
                }
            }
        }
    };

    int cur = 0;
    float hprev[4] = {0.f, 0.f, 0.f, 0.f};

    auto step = [&](int bx, int t) {
        const unsigned short* xp = &sh_x[bx][(t * MROWS + l15) * XSTR + (l4 << 3)];
        const unsigned short* hp = &sh_h[cur][l15 * XSTR + (l4 << 3)];
        bf16x8 axv[4], ahv[4];
#pragma unroll
        for (int kb = 0; kb < 4; ++kb) {
            axv[kb] = *(const bf16x8*)(xp + kb * 32);
            ahv[kb] = *(const bf16x8*)(hp + kb * 32);
        }
        f32x4 ar = {0.f, 0.f, 0.f, 0.f}, az = ar, axn = ar, ahn = ar;
#pragma unroll
        for (int kb = 0; kb < 4; ++kb) {
            ar  = __builtin_amdgcn_mfma_f32_16x16x32_bf16(axv[kb], wih[0][kb], ar,  0, 0, 0);
            az  = __builtin_amdgcn_mfma_f32_16x16x32_bf16(axv[kb], wih[1][kb], az,  0, 0, 0);
            axn = __builtin_amdgcn_mfma_f32_16x16x32_bf16(axv[kb], wih[2][kb], axn, 0, 0, 0);
            ar  = __builtin_amdgcn_mfma_f32_16x16x32_bf16(ahv[kb], whh[0][kb], ar,  0, 0, 0);
            az  = __builtin_amdgcn_mfma_f32_16x16x32_bf16(ahv[kb], whh[1][kb], az,  0, 0, 0);
            ahn = __builtin_amdgcn_mfma_f32_16x16x32_bf16(ahv[kb], whh[2][kb], ahn, 0, 0, 0);
        }
#pragma unroll
        for (int q = 0; q < 4; ++q) {
            float r = sigm(ar[q] + bias_r);
            float z = sigm(az[q] + bias_z);
            float n = tanh_f(axn[q] + bxn + r * (ahn[q] + bhn));
            float hn = (1.0f - z) * n + z * hprev[q];
            hprev[q] = hn;
            sh_h[cur ^ 1][((l4 << 2) + q) * XSTR + jj] = f2bf(hn);
        }
        __syncthreads();
        cur ^= 1;
    };

    // ---- prologue: stage chunk 0 ----
    issue(0);
    commit(0);
    __syncthreads();

    // ---- main chunked recurrence: chunks 0..14 full (16 steps each) ----
    for (int c = 0; c < 15; ++c) {
        issue((c + 1) * TCH);                 // prefetch next chunk (latency hidden by 16 steps)
        for (int t = 0; t < TCH; ++t) step(c & 1, t);
        commit((c + 1) & 1);
        __syncthreads();
    }
    // ---- final chunk: 15 steps (t = 240..254) from buffer 1 ----
    for (int t = 0; t < 15; ++t) step(1, t);

    // ================= fused MLP epilogue (LDS-resident weights) =================
    float* wl = (float*)sh_x;   // recurrence buffers dead now

    for (int i = tid; i < 8192; i += NTHR) wl[OW1 + (i >> 7) * 129 + (i & 127)] = W1[i];
    for (int i = tid; i < 2048; i += NTHR) wl[OW2 + (i >> 6) * 65  + (i & 63)]  = W2[i];
    for (int i = tid; i < 512;  i += NTHR) wl[OW3 + (i >> 5) * 33  + (i & 31)]  = W3[i];
    for (int i = tid; i < 5120; i += NTHR) wl[OWL + (i / 80) * 81  + (i % 80)]  = Wl[i];
#pragma unroll
    for (int q = 0; q < 4; ++q) wl[OHF + ((l4 << 2) + q) * 128 + jj] = hprev[q];
    __syncthreads();

    // wave wv handles batch rows 2*wv, 2*wv+1
    for (int mloc = 0; mloc < 2; ++mloc) {
        const int m = (wv << 1) + mloc;
        // stage 1: h1[64]
        {
            float s = b1[lane];
            const float* w = wl + OW1 + lane * 129;
            for (int k = 0; k < 128; ++k) s += wl[OHF + m * 128 + k] * w[k];
            wl[OS1 + wv * 64 + lane] = leaky(s);
        }
        __syncthreads();
        // stage 2: h2[32]; idle lanes gather 'last' (t = 255)
        if (lane < 32) {
            float s = b2[lane];
            const float* w = wl + OW2 + lane * 65;
            for (int k = 0; k < 64; ++k) s += wl[OS1 + wv * 64 + k] * w[k];
            wl[OS2 + wv * 32 + lane] = leaky(s);
        } else {
            int d = lane - 32;
            wl[OSL + wv * 64 + d]      = slist[((size_t)d        * CS_ + sh_idx[(m << 6) + d])      * S_ + (S_ - 1)];
            wl[OSL + wv * 64 + d + 32] = slist[((size_t)(d + 32) * CS_ + sh_idx[(m << 6) + d + 32]) * S_ + (S_ - 1)];
        }
        __syncthreads();
        // stage 3: h3[16]
        if (lane < 16) {
            float s = b3[lane];
            const float* w = wl + OW3 + lane * 33;
            for (int k = 0; k < 32; ++k) s += wl[OS2 + wv * 32 + k] * w[k];
            wl[OS3 + wv * 16 + lane] = leaky(s);
        }
        __syncthreads();
        // out = leaky(concat(h3, last) @ Wl^T + bl)
        {
            float s = bl[lane];
            const float* w = wl + OWL + lane * 81;
#pragma unroll
            for (int i = 0; i < 16; ++i) s += wl[OS3 + wv * 16 + i] * w[i];
            for (int d = 0; d < 64; ++d) s += wl[OSL + wv * 64 + d] * w[16 + d];
            out[(size_t)(bbase + m) * DIMC + lane] = leaky(s);
        }
        __syncthreads();
    }
}

extern "C" void kernel_launch(void* const* d_in, const int* in_sizes, int n_in,
                              void* d_out, int out_size, void* d_ws, size_t ws_size,
                              hipStream_t stream) {
    (void)in_sizes; (void)n_in; (void)out_size; (void)d_ws; (void)ws_size;
    const float* x       = (const float*)d_in[0];
    const int*   snippet = (const int*)  d_in[1];
    const float* slist   = (const float*)d_in[2];
    const float* W_ih    = (const float*)d_in[3];
    const float* W_hh    = (const float*)d_in[4];
    const float* b_ih    = (const float*)d_in[5];
    const float* b_hh    = (const float*)d_in[6];
    const float* W1      = (const float*)d_in[7];
    const float* b1      = (const float*)d_in[8];
    const float* W2      = (const float*)d_in[9];
    const float* b2      = (const float*)d_in[10];
    const float* W3      = (const float*)d_in[11];
    const float* b3      = (const float*)d_in[12];
    const float* Wl      = (const float*)d_in[13];
    const float* bl      = (const float*)d_in[14];
    float* out = (float*)d_out;

    hipLaunchKernelGGL(gru_fused, dim3(NBLK), dim3(NTHR), 0, stream,
                       x, snippet, slist, W_ih, W_hh, b_ih, b_hh,
                       W1, b1, W2, b2, W3, b3, Wl, bl, out);
}